// Round 9
// baseline (134.634 us; speedup 1.0000x reference)
//
#include <hip/hip_runtime.h>
#include <hip/hip_cooperative_groups.h>
#include <cfloat>

namespace cg = cooperative_groups;

// ChamferLossKL: bs=8, n=2048, d=4, fp32, one-pass over the pair matrix.
// s_ij = 2*KL(pred_i||gt_j) = dot(pa_i,ivb_j) + dot(mua_i,m2_j) + ca_i + cb_j
//   row (pred) record: pa = exp(lva)+mua^2 (4), mua (4), ca = -sum(lva)-4
//   col (gt)   record: ivb = exp(-lvb) (4), m2 = -2*mub*ivb (4),
//                      cb = sum(mub^2*ivb)+sum(lvb)
// Chain seeded with ca, cb added last -> s = 2*KL; row-min (regs+shuffle)
// and col-min (LDS ds_min_u32 on monotone encoding) of the SAME s.
// loss[b] = 0.5*(sum_i min_j s + sum_j min_i s).
//
// R8->R9: spill root-cause found. LDS 40.5KB allows 2 blocks/CU, so the
// compiler's max-occupancy heuristic targets 8 waves/EU (VGPR cap 64) and
// spills the ~95-live register tile (R4/R5/R8 all showed VGPR=56-60,
// VALUBusy 11-13%, ~100us; R7 happened to relax to 4 waves and was fast).
// launch_bounds' 2nd arg is only a FLOOR on waves/EU. Hard pin instead:
//   (1) amdgpu_waves_per_eu(4,4): occupancy target exactly 4 -> 128 VGPRs.
//   (2) static LDS padded >80KB (kept alive via asm address escape) so even
//       the compile-time ceiling is 1 block/CU. Grid is 1 block/CU anyway.
// Inner loop reverted to R7's progressive-fold (fewest live values).

#define TPB     1024
#define WAVES   16
#define RPT     8
#define ROWSPB  (WAVES * RPT)     // 128 rows per block
#define NFIX    2048
#define CH_COLS 1024              // columns per block (z-dim halves)
#define NRG     (NFIX / ROWSPB)   // 16 row groups

__device__ __forceinline__ unsigned enc_f32(float f) {
    unsigned u = __float_as_uint(f);
    return (u & 0x80000000u) ? ~u : (u | 0x80000000u);
}
__device__ __forceinline__ float dec_f32(unsigned e) {
    return (e & 0x80000000u) ? __uint_as_float(e ^ 0x80000000u)
                             : __uint_as_float(~e);
}

__global__ __launch_bounds__(TPB)
__attribute__((amdgpu_waves_per_eu(4, 4)))
void chamfer_kl_coop(
    const float4* __restrict__ mu_a, const float4* __restrict__ lv_a,
    const float4* __restrict__ mu_b, const float4* __restrict__ lv_b,
    float* __restrict__ rowpart,     // [8][2][2048]
    float* __restrict__ colpart,     // [8][16][2048]
    float* __restrict__ out)         // [8]
{
    __shared__ float4   sv0[CH_COLS];   // ivb     16 KB
    __shared__ float4   sv1[CH_COLS];   // m2      16 KB
    __shared__ float    scb[CH_COLS];   // cb       4 KB
    __shared__ unsigned scm[CH_COLS];   // enc min  4 KB
    __shared__ float    fsum[WAVES];
    __shared__ float4   lds_pad[2560];  // 40 KB pad -> total ~82 KB: forces
                                        // 1 block/CU at COMPILE time so the
                                        // allocator budget is 128 VGPRs.

    const int t    = threadIdx.x;
    const int rg   = blockIdx.x;     // 16 row groups
    const int b    = blockIdx.y;     // 8 batches
    const int ch   = blockIdx.z;     // 2 column halves
    const int lane = t & 63;
    const int wid  = t >> 6;
    const int n    = NFIX;

    // keep the pad allocated (address escapes into opaque asm)
    {
        float* pp = (float*)lds_pad;
        asm volatile("" :: "v"(pp));
    }

    // ---- stage this half's column records (gts -> B-type), 1 per thread
    {
        const int j = ch * CH_COLS + t;
        float4 mu = mu_b[(size_t)b * n + j];
        float4 lv = lv_b[(size_t)b * n + j];
        float4 iv = make_float4(__expf(-lv.x), __expf(-lv.y),
                                __expf(-lv.z), __expf(-lv.w));
        sv0[t] = iv;
        sv1[t] = make_float4(-2.f * mu.x * iv.x, -2.f * mu.y * iv.y,
                             -2.f * mu.z * iv.z, -2.f * mu.w * iv.w);
        scb[t] = mu.x * mu.x * iv.x + mu.y * mu.y * iv.y
               + mu.z * mu.z * iv.z + mu.w * mu.w * iv.w
               + lv.x + lv.y + lv.z + lv.w;
        scm[t] = 0xFFFFFFFFu;
    }

    // ---- row records (preds -> A-type), 8 rows per thread
    const int rbase = rg * ROWSPB + wid * RPT;
    float4 r0[RPT], r1[RPT];
    float  rc[RPT], rmin[RPT];
#pragma unroll
    for (int r = 0; r < RPT; ++r) {
        float4 mu = mu_a[(size_t)b * n + rbase + r];
        float4 lv = lv_a[(size_t)b * n + rbase + r];
        r0[r] = make_float4(__expf(lv.x) + mu.x * mu.x,
                            __expf(lv.y) + mu.y * mu.y,
                            __expf(lv.z) + mu.z * mu.z,
                            __expf(lv.w) + mu.w * mu.w);
        r1[r] = mu;
        rc[r] = -(lv.x + lv.y + lv.z + lv.w) - 4.f;
        rmin[r] = FLT_MAX;
    }
    __syncthreads();

    // ---- main sweep: 128 rows x 1024 cols, each pair once, s = 2*KL
    for (int jj = 0; jj < CH_COLS / 64; ++jj) {
        const int j = (jj << 6) + lane;
        const float4 c0 = sv0[j];
        const float4 c1 = sv1[j];
        const float  cb = scb[j];
        float cmin = FLT_MAX;
#pragma unroll
        for (int r = 0; r < RPT; ++r) {
            float s = fmaf(r0[r].x, c0.x, rc[r]);   // seeded with ca_i
            s = fmaf(r0[r].y, c0.y, s);
            s = fmaf(r0[r].z, c0.z, s);
            s = fmaf(r0[r].w, c0.w, s);
            s = fmaf(r1[r].x, c1.x, s);
            s = fmaf(r1[r].y, c1.y, s);
            s = fmaf(r1[r].z, c1.z, s);
            s = fmaf(r1[r].w, c1.w, s);
            s += cb;                                 // s = 2*KL(i,j)
            rmin[r] = fminf(rmin[r], s);
            cmin    = fminf(cmin, s);
        }
        atomicMin(&scm[j], enc_f32(cmin));           // ds_min_u32
    }
    __syncthreads();

    // ---- col partials for this row group (coalesced stores)
    colpart[((size_t)b * NRG + rg) * n + ch * CH_COLS + t] = dec_f32(scm[t]);

    // ---- row partials: min across 64 lanes per row
    {
        float* rp = rowpart + ((size_t)b * 2 + ch) * n + rbase;
#pragma unroll
        for (int r = 0; r < RPT; ++r) {
            float m = rmin[r];
#pragma unroll
            for (int off = 32; off; off >>= 1)
                m = fminf(m, __shfl_xor(m, off, 64));
            if (lane == 0) rp[r] = m;
        }
    }

    // ---- grid-wide barrier: all partials globally visible after this
    __threadfence();
    cg::this_grid().sync();

    // ---- finalize: one block per batch (rg==0, ch==0)
    if (rg != 0 || ch != 0) return;

    float acc = 0.f;
#pragma unroll
    for (int it = 0; it < NFIX / TPB; ++it) {   // 2 iterations
        const int j = it * TPB + t;
        float m = colpart[((size_t)b * NRG + 0) * n + j];
#pragma unroll
        for (int g = 1; g < NRG; ++g)
            m = fminf(m, colpart[((size_t)b * NRG + g) * n + j]);
        acc += m;
        acc += fminf(rowpart[((size_t)b * 2 + 0) * n + j],
                     rowpart[((size_t)b * 2 + 1) * n + j]);
    }
#pragma unroll
    for (int off = 32; off; off >>= 1) acc += __shfl_xor(acc, off, 64);
    if (lane == 0) fsum[wid] = acc;
    __syncthreads();
    if (wid == 0) {
        float v = (lane < WAVES) ? fsum[lane] : 0.f;
#pragma unroll
        for (int off = 8; off; off >>= 1) v += __shfl_xor(v, off, 64);
        if (t == 0) out[b] = 0.5f * v;
    }
}

extern "C" void kernel_launch(void* const* d_in, const int* in_sizes, int n_in,
                              void* d_out, int out_size, void* d_ws, size_t ws_size,
                              hipStream_t stream) {
    const float4* mu_a = (const float4*)d_in[0];  // mu_preds
    const float4* lv_a = (const float4*)d_in[1];  // logvar_preds
    const float4* mu_b = (const float4*)d_in[2];  // mu_gts
    const float4* lv_b = (const float4*)d_in[3];  // logvar_gts

    const int bs = out_size;  // 8

    float* ws = (float*)d_ws;
    float* colpart = ws;                              // 8*16*2048 floats (1 MB)
    float* rowpart = ws + (size_t)bs * NRG * NFIX;    // 8*2*2048 floats
    float* outp    = (float*)d_out;

    void* args[] = { (void*)&mu_a, (void*)&lv_a, (void*)&mu_b, (void*)&lv_b,
                     (void*)&rowpart, (void*)&colpart, (void*)&outp };

    dim3 grid(NRG, bs, 2);  // (16, 8, 2) = 256 blocks = 1/CU (co-resident)
    hipLaunchCooperativeKernel((void*)chamfer_kl_coop, grid, dim3(TPB),
                               args, 0, stream);
}

// Round 10
// 23.779 us; speedup vs baseline: 5.6620x; 5.6620x over previous
//
#include <hip/hip_runtime.h>
#include <cfloat>

// ChamferLossKL: bs=8, n=2048, d=4, fp32, one-pass over the pair matrix.
// s_ij = 2*KL(pred_i||gt_j) = dot(pa_i,ivb_j) + dot(mua_i,m2_j) + ca_i + cb_j
//   row (pred) record: pa = exp(lva)+mua^2 (4), mua (4), ca = -sum(lva)-4
//   col (gt)   record: ivb = exp(-lvb) (4), m2 = -2*mub*ivb (4),
//                      cb = sum(mub^2*ivb)+sum(lvb)
// Chain seeded with ca, cb added last -> s = 2*KL; row-min (regs+shuffle)
// and col-min (LDS ds_min_u32 on monotone encoding) of the SAME s.
// loss[b] = 0.5*(sum_i min_j s + sum_j min_i s).
//
// R9->R10: surrender to the allocator. Four configs (R4/R5/R8/R9) all
// allocated 56-60 VGPRs regardless of launch_bounds / amdgpu_waves_per_eu /
// LDS padding -- an RPT=8 tile (~95 live regs) ALWAYS spills on this
// toolchain (VALUBusy 11-13%, 90-120us kernels). Design for the 64-VGPR
// budget instead: RPT=4 (~55 live, fits), TPB=1024, ROWSPB=64, grid
// (32,8,2)=512 blocks = 2 blocks/CU, 8 waves/EU (better latency hiding).
// Cost model: LDS-pipe-bound ~8us main. Two-kernel structure kept from R7
// (proven 21.8us; coop/grid.sync and runtime memsets both measured slower).

#define TPB     1024
#define WAVES   16
#define RPT     4
#define ROWSPB  (WAVES * RPT)     // 64 rows per block
#define NFIX    2048
#define CH_COLS 1024              // columns per block (z-dim halves)
#define NRG     (NFIX / ROWSPB)   // 32 row groups

__device__ __forceinline__ unsigned enc_f32(float f) {
    unsigned u = __float_as_uint(f);
    return (u & 0x80000000u) ? ~u : (u | 0x80000000u);
}
__device__ __forceinline__ float dec_f32(unsigned e) {
    return (e & 0x80000000u) ? __uint_as_float(e ^ 0x80000000u)
                             : __uint_as_float(~e);
}

__global__ __launch_bounds__(TPB) void chamfer_kl_main(
    const float4* __restrict__ mu_a, const float4* __restrict__ lv_a,
    const float4* __restrict__ mu_b, const float4* __restrict__ lv_b,
    float* __restrict__ rowpart,     // [8][2][2048]
    float* __restrict__ colpart)     // [8][32][2048]
{
    __shared__ float4   sv0[CH_COLS];   // ivb     16 KB
    __shared__ float4   sv1[CH_COLS];   // m2      16 KB
    __shared__ float    scb[CH_COLS];   // cb       4 KB
    __shared__ unsigned scm[CH_COLS];   // enc min  4 KB

    const int t    = threadIdx.x;
    const int rg   = blockIdx.x;     // 32 row groups
    const int b    = blockIdx.y;     // 8 batches
    const int ch   = blockIdx.z;     // 2 column halves
    const int lane = t & 63;
    const int wid  = t >> 6;
    const int n    = NFIX;

    // ---- stage this half's column records (gts -> B-type), 1 per thread
    {
        const int j = ch * CH_COLS + t;
        float4 mu = mu_b[(size_t)b * n + j];
        float4 lv = lv_b[(size_t)b * n + j];
        float4 iv = make_float4(__expf(-lv.x), __expf(-lv.y),
                                __expf(-lv.z), __expf(-lv.w));
        sv0[t] = iv;
        sv1[t] = make_float4(-2.f * mu.x * iv.x, -2.f * mu.y * iv.y,
                             -2.f * mu.z * iv.z, -2.f * mu.w * iv.w);
        scb[t] = mu.x * mu.x * iv.x + mu.y * mu.y * iv.y
               + mu.z * mu.z * iv.z + mu.w * mu.w * iv.w
               + lv.x + lv.y + lv.z + lv.w;
        scm[t] = 0xFFFFFFFFu;
    }

    // ---- row records (preds -> A-type), 4 rows per thread (~55 live regs,
    //      fits the 64-VGPR budget the backend enforces -> no spill)
    const int rbase = rg * ROWSPB + wid * RPT;
    float4 r0[RPT], r1[RPT];
    float  rc[RPT], rmin[RPT];
#pragma unroll
    for (int r = 0; r < RPT; ++r) {
        float4 mu = mu_a[(size_t)b * n + rbase + r];
        float4 lv = lv_a[(size_t)b * n + rbase + r];
        r0[r] = make_float4(__expf(lv.x) + mu.x * mu.x,
                            __expf(lv.y) + mu.y * mu.y,
                            __expf(lv.z) + mu.z * mu.z,
                            __expf(lv.w) + mu.w * mu.w);
        r1[r] = mu;
        rc[r] = -(lv.x + lv.y + lv.z + lv.w) - 4.f;
        rmin[r] = FLT_MAX;
    }
    __syncthreads();

    // ---- main sweep: 64 rows x 1024 cols, each pair once, s = 2*KL
    for (int jj = 0; jj < CH_COLS / 64; ++jj) {
        const int j = (jj << 6) + lane;
        const float4 c0 = sv0[j];
        const float4 c1 = sv1[j];
        const float  cb = scb[j];
        float cmin = FLT_MAX;
#pragma unroll
        for (int r = 0; r < RPT; ++r) {
            float s = fmaf(r0[r].x, c0.x, rc[r]);   // seeded with ca_i
            s = fmaf(r0[r].y, c0.y, s);
            s = fmaf(r0[r].z, c0.z, s);
            s = fmaf(r0[r].w, c0.w, s);
            s = fmaf(r1[r].x, c1.x, s);
            s = fmaf(r1[r].y, c1.y, s);
            s = fmaf(r1[r].z, c1.z, s);
            s = fmaf(r1[r].w, c1.w, s);
            s += cb;                                 // s = 2*KL(i,j)
            rmin[r] = fminf(rmin[r], s);
            cmin    = fminf(cmin, s);
        }
        atomicMin(&scm[j], enc_f32(cmin));           // ds_min_u32
    }
    __syncthreads();

    // ---- col partials for this row group (coalesced stores)
    colpart[((size_t)b * NRG + rg) * n + ch * CH_COLS + t] = dec_f32(scm[t]);

    // ---- row partials: min across 64 lanes per row
    float* rp = rowpart + ((size_t)b * 2 + ch) * n + rbase;
#pragma unroll
    for (int r = 0; r < RPT; ++r) {
        float m = rmin[r];
#pragma unroll
        for (int off = 32; off; off >>= 1)
            m = fminf(m, __shfl_xor(m, off, 64));
        if (lane == 0) rp[r] = m;
    }
}

// One block per batch: sum col-mins (min over 32 row groups) plus sum of
// row-mins (min over 2 column halves). Kernel boundary = full barrier and
// visibility; out[] is overwritten (poison-safe, deterministic).
__global__ __launch_bounds__(TPB) void chamfer_kl_reduce(
    const float* __restrict__ rowpart,   // [8][2][2048]
    const float* __restrict__ colpart,   // [8][32][2048]
    float* __restrict__ out)
{
    __shared__ float fsum[WAVES];
    const int t    = threadIdx.x;
    const int b    = blockIdx.x;
    const int lane = t & 63;
    const int wid  = t >> 6;
    const int n    = NFIX;

    float acc = 0.f;
#pragma unroll
    for (int it = 0; it < NFIX / TPB; ++it) {   // 2 iterations
        const int j = it * TPB + t;
        float m = colpart[((size_t)b * NRG + 0) * n + j];
#pragma unroll
        for (int g = 1; g < NRG; ++g)
            m = fminf(m, colpart[((size_t)b * NRG + g) * n + j]);
        acc += m;
        acc += fminf(rowpart[((size_t)b * 2 + 0) * n + j],
                     rowpart[((size_t)b * 2 + 1) * n + j]);
    }
#pragma unroll
    for (int off = 32; off; off >>= 1) acc += __shfl_xor(acc, off, 64);
    if (lane == 0) fsum[wid] = acc;
    __syncthreads();
    if (wid == 0) {
        float v = (lane < WAVES) ? fsum[lane] : 0.f;
#pragma unroll
        for (int off = 8; off; off >>= 1) v += __shfl_xor(v, off, 64);
        if (t == 0) out[b] = 0.5f * v;
    }
}

extern "C" void kernel_launch(void* const* d_in, const int* in_sizes, int n_in,
                              void* d_out, int out_size, void* d_ws, size_t ws_size,
                              hipStream_t stream) {
    const float4* mu_a = (const float4*)d_in[0];  // mu_preds
    const float4* lv_a = (const float4*)d_in[1];  // logvar_preds
    const float4* mu_b = (const float4*)d_in[2];  // mu_gts
    const float4* lv_b = (const float4*)d_in[3];  // logvar_gts

    const int bs = out_size;  // 8

    float* ws = (float*)d_ws;
    float* colpart = ws;                              // 8*32*2048 floats (2 MB)
    float* rowpart = ws + (size_t)bs * NRG * NFIX;    // 8*2*2048 floats

    dim3 grid(NRG, bs, 2);  // (32, 8, 2) = 512 blocks = 2/CU, 8 waves/EU
    chamfer_kl_main<<<grid, TPB, 0, stream>>>(mu_a, lv_a, mu_b, lv_b,
                                              rowpart, colpart);
    chamfer_kl_reduce<<<bs, TPB, 0, stream>>>(rowpart, colpart, (float*)d_out);
}